// Round 1
// 80.693 us; speedup vs baseline: 1.0312x; 1.0312x over previous
//
#include <hip/hip_runtime.h>

// QuantumNAT: 4-qubit, 3-layer circuit. Reduction:
//   <Z_q> = Tr[ (W^dag Z_q W) * (rho_0 x rho_1 x rho_2 x rho_3) ]
// with rho_i = (I - sin(x_i) Y + cos(x_i) Z)/2  (RX(x)|0> has no X component).
// => <Z_q> = sum over 81 Pauli strings {I,Y,Z}^4 of coef_q[P] * prod_i m_i(P_i),
// m(I)=1, m(Y)=-sin(x_i), m(Z)=cos(x_i). coef depends only on weights.
//
// R3 (this version): prep-phase barrier count 32 -> 6.
//  - The 4 single-qubit gates of a layer commute (different qubits); the whole
//    layer incl. the CNOT chain (a pure row permutation sigma) is ONE 16x16
//    matrix: M_l[r][c] = (U_l0 x U_l1 x U_l2 x U_l3)[sigma(r)][c].
//  - W = M2*M1*M0 via two 16x16 complex matmuls (1 barrier each) instead of
//    12 sequential gate applications + 3 permutation passes (~30 barriers).
//  - All 16x16 complex LDS matrices padded to [16][17] so the 4-rows-per-wave
//    column reads in the matmul/A stages are bank-conflict-free.
//  - x4 global loads issued at kernel entry; HBM latency hides under prep.

#define NQ 4
#define NLAYERS 3
#define DIM 16
#define LDP 17          // padded leading dim (in float2) -> conflict-free cols
#define NPAULI 81
#define SPT 4
#define BLOCK 256

__device__ __forceinline__ float2 cmul(float2 a, float2 b) {
    return make_float2(a.x * b.x - a.y * b.y, a.x * b.y + a.y * b.x);
}
__device__ __forceinline__ float2 cadd(float2 a, float2 b) {
    return make_float2(a.x + b.x, a.y + b.y);
}

__global__ __launch_bounds__(256) void qnat_fused(const float4* __restrict__ x4,
                                                  const float* __restrict__ w,
                                                  float4* __restrict__ out4,
                                                  int B) {
    __shared__ float2 U[NLAYERS * NQ][4];     // 12 fused 1q gates
    __shared__ float2 M[NLAYERS][DIM][LDP];   // per-layer 16x16 (CNOT folded)
    __shared__ float2 W2[DIM][LDP];           // M1*M0
    __shared__ float2 Wm[DIM][LDP];           // full circuit W = M2*M1*M0
    __shared__ float2 A[NQ][DIM][LDP];        // A_q = W^dag Z_q W
    __shared__ float Cs[NQ * NPAULI];         // Pauli coefficients
    const int tid = threadIdx.x;
    const int base = blockIdx.x * (BLOCK * SPT) + tid;

    // ---- issue global loads first: HBM latency hides under the prep phase ----
    float4 xv[SPT];
#pragma unroll
    for (int k = 0; k < SPT; ++k) {
        int s = base + k * BLOCK;
        xv[k] = x4[s < B ? s : 0];   // clamped load; stores are guarded below
    }

    // ---------------- prep phase (redundant per block, ~1us) ----------------
    // stage 1: all 12 fused single-qubit gates U = RZ(w2) @ RY(w1) @ RX(w0)
    if (tid < NLAYERS * NQ) {
        float th0 = w[tid * 3 + 0], th1 = w[tid * 3 + 1], th2 = w[tid * 3 + 2];
        float sx, cx; __sincosf(0.5f * th0, &sx, &cx);
        float sy, cy; __sincosf(0.5f * th1, &sy, &cy);
        float sz, cz; __sincosf(0.5f * th2, &sz, &cz);
        float2 RXm[2][2], RYm[2][2], RZm[2][2], Mt[2][2];
        RXm[0][0] = make_float2(cx, 0.f);  RXm[0][1] = make_float2(0.f, -sx);
        RXm[1][0] = make_float2(0.f, -sx); RXm[1][1] = make_float2(cx, 0.f);
        RYm[0][0] = make_float2(cy, 0.f);  RYm[0][1] = make_float2(-sy, 0.f);
        RYm[1][0] = make_float2(sy, 0.f);  RYm[1][1] = make_float2(cy, 0.f);
        RZm[0][0] = make_float2(cz, -sz);  RZm[0][1] = make_float2(0.f, 0.f);
        RZm[1][0] = make_float2(0.f, 0.f); RZm[1][1] = make_float2(cz, sz);
        for (int i = 0; i < 2; ++i)
            for (int j = 0; j < 2; ++j)
                Mt[i][j] = cadd(cmul(RYm[i][0], RXm[0][j]), cmul(RYm[i][1], RXm[1][j]));
        for (int i = 0; i < 2; ++i)
            for (int j = 0; j < 2; ++j)
                U[tid][i * 2 + j] = cadd(cmul(RZm[i][0], Mt[0][j]), cmul(RZm[i][1], Mt[1][j]));
    }
    __syncthreads();

    const int r = tid >> 4, c = tid & 15;

    // stage 2: layer matrices M_l[r][c] = T_l[sigma(r)][c], CNOT perm folded.
    // sigma = s01(s12(s23(r))) exactly as the old per-layer permutation pass.
    {
        int a = r;
        if (a & 2) a ^= 1;   // s23: flip qubit3(pos0) if qubit2(pos1)
        if (a & 4) a ^= 2;   // s12
        if (a & 8) a ^= 4;   // s01
        // qubit i occupies bit (3-i); element (a_i, c_i) of gate i
        const int i0 = ((a >> 3) & 1) * 2 + ((c >> 3) & 1);
        const int i1 = ((a >> 2) & 1) * 2 + ((c >> 2) & 1);
        const int i2 = ((a >> 1) & 1) * 2 + ((c >> 1) & 1);
        const int i3 = ((a     ) & 1) * 2 + ((c     ) & 1);
#pragma unroll
        for (int l = 0; l < NLAYERS; ++l) {
            float2 m01 = cmul(U[l * 4 + 0][i0], U[l * 4 + 1][i1]);
            float2 m23 = cmul(U[l * 4 + 2][i2], U[l * 4 + 3][i3]);
            M[l][r][c] = cmul(m01, m23);
        }
    }
    __syncthreads();

    // stage 3: W2 = M1 * M0
    {
        float2 acc = make_float2(0.f, 0.f);
#pragma unroll
        for (int k = 0; k < DIM; ++k)
            acc = cadd(acc, cmul(M[1][r][k], M[0][k][c]));
        W2[r][c] = acc;
    }
    __syncthreads();

    // stage 4: Wm = M2 * W2   (full circuit unitary, encoding layer excluded)
    {
        float2 acc = make_float2(0.f, 0.f);
#pragma unroll
        for (int k = 0; k < DIM; ++k)
            acc = cadd(acc, cmul(M[2][r][k], W2[k][c]));
        Wm[r][c] = acc;
    }
    __syncthreads();

    // stage 5: A_q[j][k] = sum_b conj(W[b][j]) * z_q(b) * W[b][k]
    for (int task = tid; task < NQ * DIM * DIM; task += BLOCK) {
        int q = task >> 8, j = (task >> 4) & 15, k = task & 15;
        int pos = 3 - q;
        float2 acc = make_float2(0.f, 0.f);
#pragma unroll
        for (int b = 0; b < DIM; ++b) {
            float z = ((b >> pos) & 1) ? -1.f : 1.f;
            float2 wj = Wm[b][j], wk = Wm[b][k];
            acc.x += z * (wj.x * wk.x + wj.y * wk.y);
            acc.y += z * (wj.x * wk.y - wj.y * wk.x);
        }
        A[q][j][k] = acc;
    }
    __syncthreads();

    // stage 6: Cs[q*81 + P] = Re(Tr[A_q * PauliString(P)]) / 16
    //          digit encoding per qubit: 0=I, 1=Y, 2=Z
    for (int task = tid; task < NQ * NPAULI; task += BLOCK) {
        int q = task / NPAULI, P = task % NPAULI;
        int p0 = P / 27, p1 = (P / 9) % 3, p2 = (P / 3) % 3, p3 = P % 3;
        int p[4] = { p0, p1, p2, p3 };
        int flip = 0;
        for (int i = 0; i < 4; ++i)
            if (p[i] == 1) flip |= 1 << (3 - i);
        float accr = 0.f;
        for (int j = 0; j < DIM; ++j) {
            int k = j ^ flip;
            int ny = 0; float sgn = 1.f;
            for (int i = 0; i < 4; ++i) {
                int ji = (j >> (3 - i)) & 1;
                if (p[i] != 0 && ji) sgn = -sgn;
                if (p[i] == 1) ny++;
            }
            float phr, phi;
            switch (ny & 3) {
                case 0:  phr = sgn;  phi = 0.f;  break;
                case 1:  phr = 0.f;  phi = sgn;  break;
                case 2:  phr = -sgn; phi = 0.f;  break;
                default: phr = 0.f;  phi = -sgn; break;
            }
            float2 a = A[q][j][k];
            accr += a.x * phr - a.y * phi;   // result is real (A Hermitian)
        }
        Cs[task] = accr * (1.f / 16.f);
    }
    __syncthreads();

    // ---------------- main phase: 81-term multilinear form ----------------
    float t01[SPT][9], t23[SPT][9];
#pragma unroll
    for (int k = 0; k < SPT; ++k) {
        float s0, c0; __sincosf(xv[k].x, &s0, &c0);
        float s1, c1; __sincosf(xv[k].y, &s1, &c1);
        float s2, c2; __sincosf(xv[k].z, &s2, &c2);
        float s3, c3; __sincosf(xv[k].w, &s3, &c3);
        float m0[3] = { 1.f, -s0, c0 }, m1[3] = { 1.f, -s1, c1 };
        float m2[3] = { 1.f, -s2, c2 }, m3[3] = { 1.f, -s3, c3 };
#pragma unroll
        for (int a = 0; a < 3; ++a)
#pragma unroll
            for (int b = 0; b < 3; ++b) {
                t01[k][a * 3 + b] = m0[a] * m1[b];
                t23[k][a * 3 + b] = m2[a] * m3[b];
            }
    }

    float acc[SPT][4];
#pragma unroll
    for (int k = 0; k < SPT; ++k)
#pragma unroll
        for (int q = 0; q < 4; ++q) acc[k][q] = 0.f;

#pragma unroll
    for (int q = 0; q < 4; ++q) {
#pragma unroll
        for (int a = 0; a < 9; ++a) {
            float cf[9];
#pragma unroll
            for (int b = 0; b < 9; ++b) cf[b] = Cs[q * 81 + a * 9 + b];
#pragma unroll
            for (int k = 0; k < SPT; ++k) {
                float inner = 0.f;
#pragma unroll
                for (int b = 0; b < 9; ++b) inner = fmaf(cf[b], t23[k][b], inner);
                acc[k][q] = fmaf(t01[k][a], inner, acc[k][q]);
            }
        }
    }

#pragma unroll
    for (int k = 0; k < SPT; ++k) {
        int s = base + k * BLOCK;
        if (s < B)
            out4[s] = make_float4(acc[k][0], acc[k][1], acc[k][2], acc[k][3]);
    }
}

extern "C" void kernel_launch(void* const* d_in, const int* in_sizes, int n_in,
                              void* d_out, int out_size, void* d_ws, size_t ws_size,
                              hipStream_t stream) {
    const float* x = (const float*)d_in[0];   // [B,4] fp32
    const float* w = (const float*)d_in[1];   // [3,4,3] fp32
    float* out = (float*)d_out;               // [B,4] fp32
    int B = in_sizes[0] / 4;

    int grid = (B + BLOCK * SPT - 1) / (BLOCK * SPT);
    qnat_fused<<<grid, BLOCK, 0, stream>>>((const float4*)x, w, (float4*)out, B);
}